// Round 10
// baseline (7381.663 us; speedup 1.0000x reference)
//
#include <hip/hip_runtime.h>
#include <hip/hip_bf16.h>

typedef __attribute__((ext_vector_type(2))) _Float16 half2v;
typedef __attribute__((ext_vector_type(4))) _Float16 half4;
typedef __attribute__((ext_vector_type(4))) float f32x4;
typedef __attribute__((ext_vector_type(2))) float f32x2;

#define T_ 512
#define B_ 256
#define I_ 64
#define H_ 512
#define BH (B_ * H_)
#define NKS0 36   // K = 64(x) + 512(h1)
#define NKS1 64   // K = 512(h1) + 512(h2)

// Wp[((cb*4+w)*NKS+ks)*256 + l*4 + i] = W[g = w*512 + cb*16 + (l&15)][k = ks*16 + (l>>4)*4 + i]
template<int NKS, int K0>
__global__ void pack_w(const float* __restrict__ Wih, const float* __restrict__ Whh,
                       _Float16* __restrict__ Wp) {
    int idx = blockIdx.x * 256 + threadIdx.x;
    int i  = idx & 3;
    int l  = (idx >> 2) & 63;
    int rest = idx >> 8;
    int ks = rest % NKS;
    int r  = rest / NKS;
    int w  = r & 3;
    int cb = r >> 2;
    int g  = w * H_ + cb * 16 + (l & 15);
    int k  = ks * 16 + ((l >> 4) << 2) + i;
    float v = (k < K0) ? Wih[(size_t)g * K0 + k] : Whh[(size_t)g * H_ + (k - K0)];
    Wp[idx] = (_Float16)v;
}

// ---- device-coherent (sc0 sc1) primitives — HW-validated cross-block path ----
__device__ __forceinline__ unsigned fload(const unsigned* p) {
    unsigned v;
    asm volatile("global_load_dword %0, %1, off sc0 sc1\n\ts_waitcnt vmcnt(0)"
                 : "=&v"(v) : "v"(p) : "memory");
    return v;
}
__device__ __forceinline__ void fstore(unsigned* p, unsigned v) {
    asm volatile("global_store_dword %0, %1, off sc0 sc1" :: "v"(p), "v"(v) : "memory");
}
__device__ __forceinline__ void fstore16(void* p, f32x4 v) {
    asm volatile("global_store_dwordx4 %0, %1, off sc0 sc1" :: "v"(p), "v"(v) : "memory");
}
__device__ __forceinline__ f32x4 gload16(const void* p) {
    f32x4 v;
    asm volatile("global_load_dwordx4 %0, %1, off sc0 sc1" : "=&v"(v) : "v"(p) : "memory");
    return v;
}

__device__ __forceinline__ float sigm(float z)  { return 1.f / (1.f + __expf(-z)); }
__device__ __forceinline__ float ftanh(float z) { return 2.f / (1.f + __expf(-2.f * z)) - 1.f; }

// ---- persistent LSTM: 256 blocks x 512 threads (1 block/CU).
// 16 groups of 16 batch rows; block (gpair=bid>>5, cb=bid&31) serves groups
// 2*gpair (phase A) and 2*gpair+1 (phase B), alternating: the coherent-point
// round-trips (flag detect, tile stage, h-store ack) of one group overlap the
// compute of the other. Flag-set deferred into the next phase, after its
// stage-vmcnt(0) (which also acks this wave's previous h-stores).
// Waves 0-3: layer0 gates i,f,g,o. Waves 4-7: layer1. Per phase:
// layer0 computes h1[tt] (tt<T), layer1 computes h2[tt-1] (tt>=1).
__global__ __launch_bounds__(512, 1) void lstm_persistent(
    const float* __restrict__ x,
    const _Float16* __restrict__ Wp0, const _Float16* __restrict__ Wp1,
    const float* __restrict__ bih0, const float* __restrict__ bhh0,
    const float* __restrict__ bih1, const float* __restrict__ bhh1,
    _Float16* __restrict__ h1buf, _Float16* __restrict__ h2buf,
    unsigned* __restrict__ bar)
{
    const int bid = blockIdx.x;
    const int gpair = bid >> 5, cb = bid & 31;
    const int tid = threadIdx.x;
    const int w = tid >> 6, l = tid & 63;
    const int lr = l & 15, lk = l >> 4;
    const int c0 = cb * 16;
    const int rsw = (lr & 3) << 5;      // read-side XOR: hits the b64 4-cycle bank floor

    __shared__ __attribute__((aligned(16))) char smem[32768 + 2 * 4608 + 1024];
    char*  tile = smem;                                  // [16 rows][h1 1KB | h2 1KB]
    float* gA = (float*)(smem + 32768);                  // [4][16][18]
    float* gB = (float*)(smem + 32768 + 4608);
    _Float16* hbuf = (_Float16*)(smem + 32768 + 9216);   // [2][16][16]

    unsigned* lineA = bar + (size_t)(gpair * 2) * 64;     // 32 flags in one 128B line
    unsigned* lineB = bar + (size_t)(gpair * 2 + 1) * 64;

    // epilogue role: tid<128 -> layer0 slice, 256<=tid<384 -> layer1 slice
    int e = -1; bool elay1 = false;
    if (tid < 128) { e = tid; }
    else if (tid >= 256 && tid < 384) { e = tid - 256; elay1 = true; }
    const int er = (e >= 0) ? (e >> 3) : 0;
    const int ec = (e >= 0) ? ((e & 7) << 1) : 0;

    float br[4][2];
    {
        const float* bi = elay1 ? bih1 : bih0;
        const float* bh = elay1 ? bhh1 : bhh0;
        #pragma unroll
        for (int q = 0; q < 4; ++q)
            #pragma unroll
            for (int cc = 0; cc < 2; ++cc) {
                int gc = q * H_ + c0 + ec + cc;
                br[q][cc] = bi[gc] + bh[gc];
            }
    }

    // resident weights — single array: demand = max(36,64), not sum
    half4 breg[NKS1];
    if (w < 4) {
        const _Float16* wb = Wp0 + ((size_t)(cb * 4 + w) * NKS0) * 256 + l * 4;
        #pragma unroll
        for (int ks = 0; ks < NKS0; ++ks) breg[ks] = *(const half4*)(wb + ks * 256);
    } else {
        const _Float16* wb = Wp1 + ((size_t)(cb * 4 + (w - 4)) * NKS1) * 256 + l * 4;
        #pragma unroll
        for (int ks = 0; ks < NKS1; ++ks) breg[ks] = *(const half4*)(wb + ks * 256);
    }

    f32x2 cstA = {0.f, 0.f}, cstB = {0.f, 0.f};
    unsigned* dflag = nullptr;     // deferred flag (set in NEXT phase post-vmcnt)
    unsigned  dval  = 0;

    auto phase = [&](int tt, int R0, unsigned* line, f32x2& cst) {
        // ---- poll: all 32 blocks of this group finished step tt-1 ----
        if (tt > 0 && w == 0) {
            const unsigned tgt = (unsigned)tt;
            while (true) {
                unsigned v = fload(line + (l & 31));
                if (__all(v >= tgt)) break;
                __builtin_amdgcn_s_sleep(2);
            }
        }
        __syncthreads();

        // ---- stage tile [h1[tt-1] | h2[tt-2]] (16 rows) + x prefetch ----
        const _Float16* h1p = h1buf + ((tt + 1) & 1) * BH;
        const _Float16* h2p = h2buf + (tt & 1) * BH;
        f32x4 t[4];
        #pragma unroll
        for (int it = 0; it < 4; ++it) {
            int cch = tid + it * 512;          // 2048 x 16B chunks
            int row = cch >> 7, c = cch & 127;
            const _Float16* src = (c < 64)
                ? h1p + (size_t)(R0 + row) * H_ + (c << 3)
                : h2p + (size_t)(R0 + row) * H_ + ((c - 64) << 3);
            t[it] = gload16(src);
        }
        f32x4 xr[4];
        if (w < 4 && tt < T_) {
            const float* xa = x + (size_t)(R0 + lr) * (T_ * I_) + tt * I_ + lk * 4;
            #pragma unroll
            for (int ks = 0; ks < 4; ++ks) xr[ks] = *(const f32x4*)(xa + ks * 16);
        }
        asm volatile("s_waitcnt vmcnt(0)" ::: "memory");   // loads done; prev h-stores acked
        __builtin_amdgcn_sched_barrier(0);
        if (tid == 0 && dflag) fstore(dflag, dval);        // deferred flag of previous phase
        #pragma unroll
        for (int it = 0; it < 4; ++it) {
            int cch = tid + it * 512;
            int row = cch >> 7, c = cch & 127;
            int part = c >> 6, cc6 = c & 63;
            *(f32x4*)(tile + row * 2048 + part * 1024 + (((cc6 << 4) ^ ((row & 3) << 5)))) = t[it];
        }
        __syncthreads();

        // ---- MFMA + gate exchange ----
        if (w < 4) {
            if (tt < T_) {
                f32x4 acc = {0.f, 0.f, 0.f, 0.f};
                #pragma unroll
                for (int ks = 0; ks < 4; ++ks) {
                    half4 a = {(_Float16)xr[ks][0], (_Float16)xr[ks][1],
                               (_Float16)xr[ks][2], (_Float16)xr[ks][3]};
                    acc = __builtin_amdgcn_mfma_f32_16x16x16f16(a, breg[ks], acc, 0, 0, 0);
                }
                #pragma unroll
                for (int ks = 4; ks < NKS0; ++ks) {
                    int byte = (((ks - 4) * 32 + lk * 8) ^ rsw);
                    half4 a = *(const half4*)(tile + lr * 2048 + byte);
                    acc = __builtin_amdgcn_mfma_f32_16x16x16f16(a, breg[ks], acc, 0, 0, 0);
                }
                #pragma unroll
                for (int r = 0; r < 4; ++r)
                    gA[w * 288 + (lk * 4 + r) * 18 + lr] = acc[r];
            }
        } else {
            if (tt >= 1) {
                f32x4 acc = {0.f, 0.f, 0.f, 0.f};
                #pragma unroll
                for (int ks = 0; ks < NKS1; ++ks) {
                    int byte = ((ks & 31) * 32 + lk * 8) ^ rsw;
                    half4 a = *(const half4*)(tile + lr * 2048 + (ks >> 5) * 1024 + byte);
                    acc = __builtin_amdgcn_mfma_f32_16x16x16f16(a, breg[ks], acc, 0, 0, 0);
                }
                #pragma unroll
                for (int r = 0; r < 4; ++r)
                    gB[(w - 4) * 288 + (lk * 4 + r) * 18 + lr] = acc[r];
            }
        }
        __syncthreads();

        // ---- LSTM cell epilogue -> LDS hbuf ----
        bool act0 = (tt < T_), act1 = (tt >= 1);
        if (e >= 0 && (elay1 ? act1 : act0)) {
            const float* gb = elay1 ? gB : gA;
            f32x2 gv[4];
            #pragma unroll
            for (int q = 0; q < 4; ++q) gv[q] = *(const f32x2*)&gb[q * 288 + er * 18 + ec];
            half2v hv;
            #pragma unroll
            for (int cc = 0; cc < 2; ++cc) {
                float gi = gv[0][cc] + br[0][cc];
                float gf = gv[1][cc] + br[1][cc];
                float gg = gv[2][cc] + br[2][cc];
                float go = gv[3][cc] + br[3][cc];
                float cn = sigm(gf) * cst[cc] + sigm(gi) * ftanh(gg);
                cst[cc] = cn;
                hv[cc] = (_Float16)(sigm(go) * ftanh(cn));
            }
            *(half2v*)&hbuf[(elay1 ? 256 : 0) + er * 16 + ec] = hv;
        }
        __syncthreads();

        // ---- coalesced h stores (wave0; ack deferred to next phase's vmcnt) ----
        if (tid < 64) {
            int layer = tid >> 5;
            int row = (tid & 31) >> 1, chunk = tid & 1;
            bool act = layer ? act1 : act0;
            if (act) {
                f32x4 v = *(const f32x4*)&hbuf[layer * 256 + row * 16 + chunk * 8];
                _Float16* dst = layer ? (h2buf + ((tt + 1) & 1) * BH)   // h2[tt-1]
                                      : (h1buf + (tt & 1) * BH);        // h1[tt]
                fstore16(&dst[(size_t)(R0 + row) * H_ + c0 + chunk * 8], v);
            }
        }
        dflag = line + cb;
        dval  = (unsigned)(tt + 1);
        // no sync needed: next phase's post-poll __syncthreads orders hbuf reuse
    };

    for (int tt = 0; tt <= T_; ++tt) {
        phase(tt, gpair * 32,      lineA, cstA);
        phase(tt, gpair * 32 + 16, lineB, cstB);
    }
}

__global__ void fc_kernel(const _Float16* __restrict__ h2, const float* __restrict__ Wfc,
                          const float* __restrict__ bfc, float* __restrict__ out) {
    int b = blockIdx.x;
    int lidx = threadIdx.x;
    float s = 0.f;
    #pragma unroll
    for (int h = lidx; h < H_; h += 64) s += (float)h2[b * H_ + h] * Wfc[h];
    #pragma unroll
    for (int off = 32; off; off >>= 1) s += __shfl_down(s, off);
    if (lidx == 0) out[b] = s + bfc[0];
}

extern "C" void kernel_launch(void* const* d_in, const int* in_sizes, int n_in,
                              void* d_out, int out_size, void* d_ws, size_t ws_size,
                              hipStream_t stream) {
    const float* x    = (const float*)d_in[0];
    const float* Wih0 = (const float*)d_in[1];
    const float* Whh0 = (const float*)d_in[2];
    const float* bih0 = (const float*)d_in[3];
    const float* bhh0 = (const float*)d_in[4];
    const float* Wih1 = (const float*)d_in[5];
    const float* Whh1 = (const float*)d_in[6];
    const float* bih1 = (const float*)d_in[7];
    const float* bhh1 = (const float*)d_in[8];
    const float* Wfc  = (const float*)d_in[9];
    const float* bfc  = (const float*)d_in[10];
    float* out = (float*)d_out;

    char* ws = (char*)d_ws;
    unsigned*  bar   = (unsigned*)ws;                       // 4 KB: 16 group flag-lines (256B apart)
    _Float16*  h1buf = (_Float16*)(ws + 4096);              // 2 x 256 KB
    _Float16*  h2buf = (_Float16*)(ws + 4096 + 524288);     // 2 x 256 KB
    _Float16*  Wp0   = (_Float16*)(ws + 4096 + 1048576);    // 2359296 B
    _Float16*  Wp1   = (_Float16*)(ws + 4096 + 1048576 + 2359296);  // 4194304 B

    hipMemsetAsync(d_ws, 0, 4096 + 1048576, stream);   // flags + h parity buffers
    pack_w<NKS0, I_><<<4608, 256, 0, stream>>>(Wih0, Whh0, Wp0);
    pack_w<NKS1, H_><<<8192, 256, 0, stream>>>(Wih1, Whh1, Wp1);

    lstm_persistent<<<dim3(256), dim3(512), 0, stream>>>(
        x, Wp0, Wp1, bih0, bhh0, bih1, bhh1, h1buf, h2buf, bar);

    fc_kernel<<<B_, 64, 0, stream>>>(h2buf + BH, Wfc, bfc, out);
}

// Round 11
// 4219.701 us; speedup vs baseline: 1.7493x; 1.7493x over previous
//
#include <hip/hip_runtime.h>
#include <hip/hip_bf16.h>

typedef __attribute__((ext_vector_type(2))) _Float16 half2v;
typedef __attribute__((ext_vector_type(4))) _Float16 half4;
typedef __attribute__((ext_vector_type(4))) float f32x4;
typedef __attribute__((ext_vector_type(2))) float f32x2;

#define T_ 512
#define B_ 256
#define I_ 64
#define H_ 512
#define BH (B_ * H_)
#define NKS0 36   // K = 64(x) + 512(h1)
#define NKS1 64   // K = 512(h1) + 512(h2)

// Wp[((cb*4+w)*NKS+ks)*256 + l*4 + i] = W[g = w*512 + cb*16 + (l&15)][k = ks*16 + (l>>4)*4 + i]
template<int NKS, int K0>
__global__ void pack_w(const float* __restrict__ Wih, const float* __restrict__ Whh,
                       _Float16* __restrict__ Wp) {
    int idx = blockIdx.x * 256 + threadIdx.x;
    int i  = idx & 3;
    int l  = (idx >> 2) & 63;
    int rest = idx >> 8;
    int ks = rest % NKS;
    int r  = rest / NKS;
    int w  = r & 3;
    int cb = r >> 2;
    int g  = w * H_ + cb * 16 + (l & 15);
    int k  = ks * 16 + ((l >> 4) << 2) + i;
    float v = (k < K0) ? Wih[(size_t)g * K0 + k] : Whh[(size_t)g * H_ + (k - K0)];
    Wp[idx] = (_Float16)v;
}

// ---- MALL (device-coherent) primitives — HW-validated rounds 4-9 ----
__device__ __forceinline__ unsigned fload(const unsigned* p) {
    unsigned v;
    asm volatile("global_load_dword %0, %1, off sc0 sc1\n\ts_waitcnt vmcnt(0)"
                 : "=&v"(v) : "v"(p) : "memory");
    return v;
}
__device__ __forceinline__ void fstore(unsigned* p, unsigned v) {
    asm volatile("global_store_dword %0, %1, off sc0 sc1" :: "v"(p), "v"(v) : "memory");
}
// ---- h-data primitives: FAST = XCD-local L2 (sc0: L1-bypass, L2 home);
//      SLOW = MALL bypass (sc0 sc1), identical to round 9 ----
template<bool FAST> __device__ __forceinline__ f32x4 gload16(const void* p) {
    f32x4 v;
    if (FAST) asm volatile("global_load_dwordx4 %0, %1, off sc0" : "=&v"(v) : "v"(p) : "memory");
    else      asm volatile("global_load_dwordx4 %0, %1, off sc0 sc1" : "=&v"(v) : "v"(p) : "memory");
    return v;
}
template<bool FAST> __device__ __forceinline__ void fstore16(void* p, f32x4 v) {
    if (FAST) asm volatile("global_store_dwordx4 %0, %1, off sc0" :: "v"(p), "v"(v) : "memory");
    else      asm volatile("global_store_dwordx4 %0, %1, off sc0 sc1" :: "v"(p), "v"(v) : "memory");
}

__device__ __forceinline__ float sigm(float z)  { return 1.f / (1.f + __expf(-z)); }

// ---- the persistent time loop (round-9 structure; scope templated) ----
template<bool FAST>
__device__ __forceinline__ void run_lstm(
    int g, int cb, char* smem,
    const float* __restrict__ x,
    const _Float16* __restrict__ Wp0, const _Float16* __restrict__ Wp1,
    const float* __restrict__ bih0, const float* __restrict__ bhh0,
    const float* __restrict__ bih1, const float* __restrict__ bhh1,
    _Float16* __restrict__ h1buf, _Float16* __restrict__ h2buf,
    unsigned* __restrict__ bar)
{
    const int tid = threadIdx.x;
    const int w = tid >> 6, l = tid & 63;
    const int lr = l & 15, lk = l >> 4;
    const int R0 = g * 32, c0 = cb * 16;
    const int xsw = lr << 4;            // read-side XOR (16B granule), rows lr / lr+16 share it

    float* gA = (float*)(smem + 65536);             // [4][32][18] layer0 gate exchange
    float* gB = (float*)(smem + 65536 + 9216);      // [4][32][18] layer1
    _Float16* hbuf = (_Float16*)(smem + 83968);     // [2][32][16] h staging for coalesced store

    unsigned* grpline = bar + (size_t)g * 64;       // 32 flags in one 128B line
    unsigned* myflag  = grpline + cb;

    const int er = (tid >> 3) & 31;
    const int ec = (tid & 7) << 1;
    const bool lay1 = tid >= 256;

    float br[4][2];
    {
        const float* bi = lay1 ? bih1 : bih0;
        const float* bh = lay1 ? bhh1 : bhh0;
        #pragma unroll
        for (int q = 0; q < 4; ++q)
            #pragma unroll
            for (int cc = 0; cc < 2; ++cc) {
                int gc = q * H_ + c0 + ec + cc;
                br[q][cc] = bi[gc] + bh[gc];
            }
    }

    // resident weights — single array: demand = max(36,64) regs, not sum
    half4 breg[NKS1];
    if (w < 4) {
        const _Float16* wb = Wp0 + ((size_t)(cb * 4 + w) * NKS0) * 256 + l * 4;
        #pragma unroll
        for (int ks = 0; ks < NKS0; ++ks) breg[ks] = *(const half4*)(wb + ks * 256);
    } else {
        const _Float16* wb = Wp1 + ((size_t)(cb * 4 + (w - 4)) * NKS1) * 256 + l * 4;
        #pragma unroll
        for (int ks = 0; ks < NKS1; ++ks) breg[ks] = *(const half4*)(wb + ks * 256);
    }

    f32x2 cstr = {0.f, 0.f};

    for (int tt = 0; tt <= T_; ++tt) {
        // x prefetch (plain cached loads, immutable data)
        f32x4 xr0[4], xr1[4];
        if (w < 4 && tt < T_) {
            const float* xa = x + (size_t)(R0 + lr) * (T_ * I_) + tt * I_ + lk * 4;
            const float* xb = x + (size_t)(R0 + 16 + lr) * (T_ * I_) + tt * I_ + lk * 4;
            #pragma unroll
            for (int ks = 0; ks < 4; ++ks) {
                xr0[ks] = *(const f32x4*)(xa + ks * 16);
                xr1[ks] = *(const f32x4*)(xb + ks * 16);
            }
        }

        // ---- wait: all 32 group blocks finished step tt-1 (ONE coalesced poll) ----
        if (tt > 0 && w == 0) {
            const unsigned tgt = (unsigned)tt;
            while (true) {
                unsigned v = fload(grpline + (l & 31));
                if (__all(v >= tgt)) break;
                __builtin_amdgcn_s_sleep(4);
            }
        }
        __syncthreads();

        // ---- stage tile = [ h1[tt-1] | h2[tt-2] ], swizzled g16 ^= row&15 ----
        {
            const _Float16* h1p = h1buf + ((tt + 1) & 1) * BH;
            const _Float16* h2p = h2buf + (tt & 1) * BH;
            f32x4 t[8];
            #pragma unroll
            for (int it = 0; it < 8; ++it) {
                int cch = tid + it * 512;          // 16B granules, 4096 total
                int row = cch >> 7, g16 = cch & 127;
                const _Float16* src = (g16 < 64)
                    ? h1p + (size_t)(R0 + row) * H_ + (g16 << 3)
                    : h2p + (size_t)(R0 + row) * H_ + ((g16 - 64) << 3);
                t[it] = gload16<FAST>(src);
            }
            asm volatile("s_waitcnt vmcnt(0)" ::: "memory");
            __builtin_amdgcn_sched_barrier(0);
            #pragma unroll
            for (int it = 0; it < 8; ++it) {
                int cch = tid + it * 512;
                int row = cch >> 7, g16 = cch & 127;
                *(f32x4*)(smem + row * 2048 + ((g16 ^ (row & 15)) << 4)) = t[it];
            }
        }
        __syncthreads();

        // ---- MFMA + gate exchange ----
        if (w < 4) {
            if (tt < T_) {
                f32x4 acc0 = {0.f,0.f,0.f,0.f}, acc1 = {0.f,0.f,0.f,0.f};
                #pragma unroll
                for (int ks = 0; ks < 4; ++ks) {
                    half4 a0 = {(_Float16)xr0[ks][0], (_Float16)xr0[ks][1], (_Float16)xr0[ks][2], (_Float16)xr0[ks][3]};
                    half4 a1 = {(_Float16)xr1[ks][0], (_Float16)xr1[ks][1], (_Float16)xr1[ks][2], (_Float16)xr1[ks][3]};
                    acc0 = __builtin_amdgcn_mfma_f32_16x16x16f16(a0, breg[ks], acc0, 0, 0, 0);
                    acc1 = __builtin_amdgcn_mfma_f32_16x16x16f16(a1, breg[ks], acc1, 0, 0, 0);
                }
                #pragma unroll
                for (int ks = 4; ks < NKS0; ++ks) {
                    int cbyte = ((ks - 4) * 32 + lk * 8) ^ xsw;
                    half4 a0 = *(const half4*)(smem + lr * 2048 + cbyte);
                    half4 a1 = *(const half4*)(smem + (lr + 16) * 2048 + cbyte);
                    acc0 = __builtin_amdgcn_mfma_f32_16x16x16f16(a0, breg[ks], acc0, 0, 0, 0);
                    acc1 = __builtin_amdgcn_mfma_f32_16x16x16f16(a1, breg[ks], acc1, 0, 0, 0);
                }
                float* gb = gA + w * 576;
                #pragma unroll
                for (int r = 0; r < 4; ++r) {
                    gb[(lk * 4 + r) * 18 + lr]      = acc0[r];
                    gb[(16 + lk * 4 + r) * 18 + lr] = acc1[r];
                }
            }
        } else {
            if (tt >= 1) {
                f32x4 acc0 = {0.f,0.f,0.f,0.f}, acc1 = {0.f,0.f,0.f,0.f};
                #pragma unroll
                for (int ks = 0; ks < NKS1; ++ks) {
                    int cbyte = (ks * 32 + lk * 8) ^ xsw;
                    half4 a0 = *(const half4*)(smem + lr * 2048 + cbyte);
                    half4 a1 = *(const half4*)(smem + (lr + 16) * 2048 + cbyte);
                    acc0 = __builtin_amdgcn_mfma_f32_16x16x16f16(a0, breg[ks], acc0, 0, 0, 0);
                    acc1 = __builtin_amdgcn_mfma_f32_16x16x16f16(a1, breg[ks], acc1, 0, 0, 0);
                }
                float* gb = gB + (w - 4) * 576;
                #pragma unroll
                for (int r = 0; r < 4; ++r) {
                    gb[(lk * 4 + r) * 18 + lr]      = acc0[r];
                    gb[(16 + lk * 4 + r) * 18 + lr] = acc1[r];
                }
            }
        }
        __syncthreads();

        // ---- LSTM cell epilogue -> LDS hbuf ----
        {
            const float* gb = lay1 ? gB : gA;
            f32x2 gv[4];
            #pragma unroll
            for (int q = 0; q < 4; ++q) gv[q] = *(const f32x2*)&gb[q * 576 + er * 18 + ec];
            half2v hv;
            #pragma unroll
            for (int cc = 0; cc < 2; ++cc) {
                float gi = gv[0][cc] + br[0][cc];
                float gf = gv[1][cc] + br[1][cc];
                float gg = gv[2][cc] + br[2][cc];
                float go = gv[3][cc] + br[3][cc];
                float si = sigm(gi);
                float sf = sigm(gf);
                float tg = tanhf(gg);
                float so = sigm(go);
                float cn = sf * cstr[cc] + si * tg;
                bool act = lay1 ? (tt >= 1) : (tt < T_);
                if (act) cstr[cc] = cn;
                float th = tanhf(cn);
                hv[cc] = (_Float16)(so * th);
            }
            *(half2v*)&hbuf[(lay1 ? 512 : 0) + er * 16 + ec] = hv;
        }
        __syncthreads();

        // ---- coalesced 16B h stores (threads 0-127) ----
        if (tid < 128) {
            int layer = tid >> 6;
            int row = (tid & 63) >> 1, chunk = tid & 1;
            bool act = layer ? (tt >= 1) : (tt < T_);
            if (act) {
                f32x4 v = *(const f32x4*)&hbuf[layer * 512 + row * 16 + chunk * 8];
                _Float16* dst = layer
                    ? (h2buf + ((tt + 1) & 1) * BH)   // h2[tt-1]
                    : (h1buf + (tt & 1) * BH);        // h1[tt]
                fstore16<FAST>(&dst[(size_t)(R0 + row) * H_ + c0 + chunk * 8], v);
            }
        }
        asm volatile("s_waitcnt vmcnt(0)" ::: "memory");   // h stores retired (L2 or MALL)
        __syncthreads();

        // ---- arrival flag (MALL; after h visible at its coherence home) ----
        if (tt < T_ && tid == 0) fstore(myflag, (unsigned)(tt + 1));
    }
}

// ---- kernel: XCD rendezvous with SINGLE-SOURCE verdict (deadlock-free) ----
__global__ __launch_bounds__(512, 1) void lstm_persistent(
    const float* __restrict__ x,
    const _Float16* __restrict__ Wp0, const _Float16* __restrict__ Wp1,
    const float* __restrict__ bih0, const float* __restrict__ bhh0,
    const float* __restrict__ bih1, const float* __restrict__ bhh1,
    _Float16* __restrict__ h1buf, _Float16* __restrict__ h2buf,
    unsigned* __restrict__ bar, unsigned* __restrict__ ctrl)
{
    __shared__ __attribute__((aligned(16))) char smem[65536 + 2 * 9216 + 2048];
    __shared__ int sinfo[3];
    const int bid = blockIdx.x;

    if (threadIdx.x == 0) {
        // HW_REG_XCC_ID = 20 (gfx940+), offset 0, size 8
        unsigned xcd = __builtin_amdgcn_s_getreg(20 | (7 << 11)) & 7u;
        unsigned slot = __hip_atomic_fetch_add(&ctrl[xcd], 1u,
                          __ATOMIC_RELAXED, __HIP_MEMORY_SCOPE_AGENT);
        __hip_atomic_fetch_add(&ctrl[8], 1u, __ATOMIC_RELAXED, __HIP_MEMORY_SCOPE_AGENT);
        // bounded wait for all arrivals (all 256 blocks are resident -> fast)
        for (int it = 0; it < 100000; ++it) {
            if (__hip_atomic_load(&ctrl[8], __ATOMIC_RELAXED, __HIP_MEMORY_SCOPE_AGENT) >= 256u)
                break;
            __builtin_amdgcn_s_sleep(8);
        }
        if (bid == 0) {
            // single-source verdict: only block 0 decides, then publishes
            unsigned ok = 2u;
            #pragma unroll
            for (int k = 0; k < 8; ++k)
                if (__hip_atomic_load(&ctrl[k], __ATOMIC_RELAXED, __HIP_MEMORY_SCOPE_AGENT) != 32u)
                    ok = 1u;
            __hip_atomic_store(&ctrl[9], ok, __ATOMIC_RELAXED, __HIP_MEMORY_SCOPE_AGENT);
        }
        unsigned verdict;
        while ((verdict = __hip_atomic_load(&ctrl[9], __ATOMIC_RELAXED,
                                            __HIP_MEMORY_SCOPE_AGENT)) == 0u)
            __builtin_amdgcn_s_sleep(8);
        sinfo[0] = (verdict == 2u);
        sinfo[1] = (int)xcd;
        sinfo[2] = (int)slot;
    }
    __syncthreads();

    if (sinfo[0]) {
        run_lstm<true>(sinfo[1], sinfo[2], smem, x, Wp0, Wp1,
                       bih0, bhh0, bih1, bhh1, h1buf, h2buf, bar);
    } else {
        run_lstm<false>(bid >> 5, bid & 31, smem, x, Wp0, Wp1,
                        bih0, bhh0, bih1, bhh1, h1buf, h2buf, bar);
    }
}

__global__ void fc_kernel(const _Float16* __restrict__ h2, const float* __restrict__ Wfc,
                          const float* __restrict__ bfc, float* __restrict__ out) {
    int b = blockIdx.x;
    int lidx = threadIdx.x;
    float s = 0.f;
    #pragma unroll
    for (int h = lidx; h < H_; h += 64) s += (float)h2[b * H_ + h] * Wfc[h];
    #pragma unroll
    for (int off = 32; off; off >>= 1) s += __shfl_down(s, off);
    if (lidx == 0) out[b] = s + bfc[0];
}

extern "C" void kernel_launch(void* const* d_in, const int* in_sizes, int n_in,
                              void* d_out, int out_size, void* d_ws, size_t ws_size,
                              hipStream_t stream) {
    const float* x    = (const float*)d_in[0];
    const float* Wih0 = (const float*)d_in[1];
    const float* Whh0 = (const float*)d_in[2];
    const float* bih0 = (const float*)d_in[3];
    const float* bhh0 = (const float*)d_in[4];
    const float* Wih1 = (const float*)d_in[5];
    const float* Whh1 = (const float*)d_in[6];
    const float* bih1 = (const float*)d_in[7];
    const float* bhh1 = (const float*)d_in[8];
    const float* Wfc  = (const float*)d_in[9];
    const float* bfc  = (const float*)d_in[10];
    float* out = (float*)d_out;

    char* ws = (char*)d_ws;
    unsigned*  bar   = (unsigned*)ws;                       // 2 KB: 8 group flag-lines (256B apart)
    unsigned*  ctrl  = (unsigned*)(ws + 2048);              // 64 B: xcd counters + arrivals + verdict
    _Float16*  h1buf = (_Float16*)(ws + 4096);              // 2 x 256 KB
    _Float16*  h2buf = (_Float16*)(ws + 4096 + 524288);     // 2 x 256 KB
    _Float16*  Wp0   = (_Float16*)(ws + 4096 + 1048576);    // 2359296 B
    _Float16*  Wp1   = (_Float16*)(ws + 4096 + 1048576 + 2359296);  // 4194304 B

    hipMemsetAsync(d_ws, 0, 4096 + 1048576, stream);   // flags + ctrl + h parity buffers
    pack_w<NKS0, I_><<<4608, 256, 0, stream>>>(Wih0, Whh0, Wp0);
    pack_w<NKS1, H_><<<8192, 256, 0, stream>>>(Wih1, Whh1, Wp1);

    lstm_persistent<<<dim3(256), dim3(512), 0, stream>>>(
        x, Wp0, Wp1, bih0, bhh0, bih1, bhh1, h1buf, h2buf, bar, ctrl);

    fc_kernel<<<B_, 64, 0, stream>>>(h2buf + BH, Wfc, bfc, out);
}